// Round 13
// baseline (946.832 us; speedup 1.0000x reference)
//
#include <hip/hip_runtime.h>
#include <hip/hip_bf16.h>
#include <hip/hip_fp16.h>

typedef float f4 __attribute__((ext_vector_type(4)));
typedef unsigned int u32x2 __attribute__((ext_vector_type(2)));
typedef unsigned int u32x4 __attribute__((ext_vector_type(4)));
typedef _Float16 h8 __attribute__((ext_vector_type(8)));

__device__ __forceinline__ __half2 bits2h2(unsigned u) {
    union { unsigned u; __half2 h; } c; c.u = u; return c.h;
}
__device__ __forceinline__ unsigned h22bits(__half2 h) {
    union { unsigned u; __half2 h; } c; c.h = h; return c.u;
}

#define N_NODES   100000
#define EMBED     128
#define N_USERS_T 50000
#define N_ITEMS   50000

#define BSH   8                 // bucket = dst >> 8
#define NB    391               // ceil(100000 / 256)
#define NBLK  256               // partition blocks

// ---------- K1: per-block bucket histogram ----------
__global__ __launch_bounds__(256) void part_hist(const int* __restrict__ dst,
                                                 int* __restrict__ blkhist,
                                                 int n, int epb) {
    __shared__ int h[NB];
    for (int j = threadIdx.x; j < NB; j += 256) h[j] = 0;
    __syncthreads();
    int b = blockIdx.x, s = b * epb, e = min(n, s + epb);
    for (int i = s + (int)threadIdx.x; i < e; i += 256)
        atomicAdd(&h[dst[i] >> BSH], 1);
    __syncthreads();
    for (int j = threadIdx.x; j < NB; j += 256) blkhist[b * NB + j] = h[j];
}

// ---------- K2a: per-bucket exclusive scan across blocks ----------
__global__ __launch_bounds__(256) void part_cursors(const int* __restrict__ blkhist,
                                                    int* __restrict__ cursors,
                                                    int* __restrict__ total) {
    int bu = blockIdx.x, t = threadIdx.x;
    int v = blkhist[t * NB + bu];
    int lane = t & 63, wid = t >> 6;
    int x = v;
    #pragma unroll
    for (int off = 1; off < 64; off <<= 1) {
        int y = __shfl_up(x, off, 64);
        if (lane >= off) x += y;
    }
    __shared__ int ws4[4];
    if (lane == 63) ws4[wid] = x;
    __syncthreads();
    int add = 0;
    for (int j = 0; j < wid; ++j) add += ws4[j];
    cursors[t * NB + bu] = add + x - v;      // exclusive over blocks
    if (t == 255) total[bu] = add + x;       // bucket size
}

// ---------- K2b: bucket base (serial tiny scan) ----------
__global__ void bucket_base_scan(const int* __restrict__ total,
                                 int* __restrict__ base) {
    if (threadIdx.x == 0) {
        int s = 0;
        for (int j = 0; j < NB; ++j) { base[j] = s; s += total[j]; }
        base[NB] = s;
    }
}

// ---------- K3: partition into buckets (block-private slices) ----------
// part entry: .x = src | (dst_low8 << 17), .y = w bits
__global__ __launch_bounds__(256) void part_scatter(const int* __restrict__ src,
                                                    const int* __restrict__ dst,
                                                    const float* __restrict__ w,
                                                    const int* __restrict__ cursors,
                                                    const int* __restrict__ base,
                                                    int2* __restrict__ part,
                                                    int n, int epb) {
    __shared__ int cur[NB];
    int b = blockIdx.x;
    for (int j = threadIdx.x; j < NB; j += 256)
        cur[j] = base[j] + cursors[b * NB + j];
    __syncthreads();
    int s = b * epb, e = min(n, s + epb);
    for (int i = s + (int)threadIdx.x; i < e; i += 256) {
        int d = dst[i];
        int bu = d >> BSH;
        int p = atomicAdd(&cur[bu], 1);
        int2 pe;
        pe.x = src[i] | ((d & 255) << 17);
        pe.y = __float_as_int(w[i]);
        part[p] = pe;
    }
}

// ---------- K4: per-bucket fine CSR; emits compressed edge u32 -------------
// edge u32 = src (17b) | wq (15b fixed-point w*32768)
__global__ __launch_bounds__(512) void bucket_csr(const int2* __restrict__ part,
                                                  const int* __restrict__ base,
                                                  int* __restrict__ off_end,
                                                  unsigned* __restrict__ ep,
                                                  int n_nodes) {
    __shared__ int cnt[256], cur2[256], ws4[4];
    int bu = blockIdx.x, t = threadIdx.x;
    int b0 = base[bu], b1 = base[bu + 1];
    if (t < 256) cnt[t] = 0;
    __syncthreads();
    for (int i = b0 + t; i < b1; i += 512)
        atomicAdd(&cnt[(part[i].x >> 17) & 255], 1);
    __syncthreads();
    int lane = t & 63, wid = t >> 6;
    int v = 0, x = 0;
    if (t < 256) {
        v = cnt[t]; x = v;
        #pragma unroll
        for (int off = 1; off < 64; off <<= 1) {
            int y = __shfl_up(x, off, 64);
            if (lane >= off) x += y;
        }
        if (lane == 63) ws4[wid] = x;
    }
    __syncthreads();
    if (t < 256) {
        int add = 0;
        for (int j = 0; j < wid; ++j) add += ws4[j];
        int incl = add + x;
        int node = (bu << BSH) + t;
        if (node < n_nodes) off_end[node] = b0 + incl;
        cur2[t] = b0 + incl - v;             // exclusive start
    }
    __syncthreads();
    for (int i = b0 + t; i < b1; i += 512) {
        int2 pe = part[i];
        int dloc = (pe.x >> 17) & 255;
        int p = atomicAdd(&cur2[dloc], 1);
        float wf = __int_as_float(pe.y);
        int wq = (int)(wf * 32768.f + 0.5f);
        wq = min(max(wq, 0), 32767);
        ep[p] = (unsigned)(pe.x & 0x1FFFF) | ((unsigned)wq << 17);
    }
}

// ---------- fp32 -> fp16, SLICED layout [8][N][16] ----------
__global__ __launch_bounds__(256) void f2h_slice(const float* __restrict__ in,
                                                 __half* __restrict__ out,
                                                 int n_nodes) {
    int s = blockIdx.y;
    int t = blockIdx.x * 256 + threadIdx.x;     // over n_nodes*4
    if (t >= n_nodes * 4) return;
    int node = t >> 2, wq = t & 3;
    f4 v = *(const f4*)(in + (size_t)node * EMBED + s * 16 + wq * 4);
    u32x2 o;
    o.x = h22bits(__floats2half2_rn(v.x, v.y));
    o.y = h22bits(__floats2half2_rn(v.z, v.w));
    ((u32x2*)out)[((size_t)s * n_nodes + node) * 4 + wq] = o;
}

// ---------- sliced propagation layer ----------
// Feature-sharded: slice = blockIdx.x & 7 -> under round-robin block->XCD
// dispatch, all blocks of slice s run on XCD s; slice working set = N*32 B
// = 3.2 MB < 4 MB per-XCD L2 -> gathers become L2-resident. Slice-major
// layout [8][N][16] keeps 128-B cache lines entirely within one slice.
// Each 2-lane group owns one node, walking its edge list serially (no
// cross-lane reduce, no shfl, no uniform-trip-count hazard). Edge meta is
// re-read per slice (8 x 12.8 MB/layer) via nt-loads to limit L2 pollution.
__global__ __launch_bounds__(256) void layer_slice(
        const __half* __restrict__ rin, __half* __restrict__ rout,
        const int* __restrict__ off_end, const unsigned* __restrict__ ep,
        int n_nodes) {
    int s    = blockIdx.x & 7;
    int nb   = blockIdx.x >> 3;
    int lane = threadIdx.x & 63;
    int node = nb * 128 + (threadIdx.x >> 6) * 32 + (lane >> 1);
    if (node >= n_nodes) return;
    int h = lane & 1;                    // 16-B half of the 32-B node-slice
    int beg = (node == 0) ? 0 : off_end[node - 1];
    int end = off_end[node];
    const u32x4* rp = (const u32x4*)(rin + (size_t)s * n_nodes * 16);
    u32x4*       wp = (u32x4*)(rout + (size_t)s * n_nodes * 16);
    f4 sa = {0.f, 0.f, 0.f, 0.f};
    f4 sb = {0.f, 0.f, 0.f, 0.f};

    auto acc1 = [&](unsigned v, u32x4 rv) {
        float wt = (float)(v >> 17) * (1.f / 32768.f);
        float2 f0 = __half22float2(bits2h2(rv.x));
        float2 f1 = __half22float2(bits2h2(rv.y));
        float2 f2 = __half22float2(bits2h2(rv.z));
        float2 f3 = __half22float2(bits2h2(rv.w));
        sa.x = fmaf(wt, f0.x, sa.x); sa.y = fmaf(wt, f0.y, sa.y);
        sa.z = fmaf(wt, f1.x, sa.z); sa.w = fmaf(wt, f1.y, sa.w);
        sb.x = fmaf(wt, f2.x, sb.x); sb.y = fmaf(wt, f2.y, sb.y);
        sb.z = fmaf(wt, f3.x, sb.z); sb.w = fmaf(wt, f3.y, sb.w);
    };

    int e = beg;
    for (; e + 4 <= end; e += 4) {
        unsigned v0 = __builtin_nontemporal_load(ep + e);
        unsigned v1 = __builtin_nontemporal_load(ep + e + 1);
        unsigned v2 = __builtin_nontemporal_load(ep + e + 2);
        unsigned v3 = __builtin_nontemporal_load(ep + e + 3);
        u32x4 r0 = rp[(v0 & 0x1FFFF) * 2 + h];
        u32x4 r1 = rp[(v1 & 0x1FFFF) * 2 + h];
        u32x4 r2 = rp[(v2 & 0x1FFFF) * 2 + h];
        u32x4 r3 = rp[(v3 & 0x1FFFF) * 2 + h];
        acc1(v0, r0); acc1(v1, r1); acc1(v2, r2); acc1(v3, r3);
    }
    for (; e < end; ++e) {
        unsigned v = __builtin_nontemporal_load(ep + e);
        u32x4 r = rp[(v & 0x1FFFF) * 2 + h];
        acc1(v, r);
    }
    u32x4 ov;
    ov.x = h22bits(__floats2half2_rn(sa.x, sa.y));
    ov.y = h22bits(__floats2half2_rn(sa.z, sa.w));
    ov.z = h22bits(__floats2half2_rn(sb.x, sb.y));
    ov.w = h22bits(__floats2half2_rn(sb.z, sb.w));
    wp[(size_t)node * 2 + h] = ov;
}

// ---------- final user rows: 0.25*(emb + r1 + r2 + r3), sliced reads ------
__global__ __launch_bounds__(256) void gather_users(const int* __restrict__ users,
                                                    const __half* __restrict__ embS,
                                                    const __half* __restrict__ r1,
                                                    const __half* __restrict__ r2,
                                                    const __half* __restrict__ r3,
                                                    _Float16* __restrict__ ur,
                                                    int nu, int n_nodes) {
    int idx = blockIdx.x * 256 + threadIdx.x;
    int u = idx >> 5;
    int q = idx & 31;
    if (u >= nu) return;
    size_t row = (size_t)users[u];
    int sl = q >> 2, wq = q & 3;
    size_t p = ((size_t)sl * n_nodes + row) * 4 + wq;
    u32x2 e = ((const u32x2*)embS)[p];
    u32x2 a = ((const u32x2*)r1)[p];
    u32x2 b = ((const u32x2*)r2)[p];
    u32x2 c = ((const u32x2*)r3)[p];
    float2 e0 = __half22float2(bits2h2(e.x)), e1 = __half22float2(bits2h2(e.y));
    float2 a0 = __half22float2(bits2h2(a.x)), a1 = __half22float2(bits2h2(a.y));
    float2 b0 = __half22float2(bits2h2(b.x)), b1 = __half22float2(bits2h2(b.y));
    float2 c0 = __half22float2(bits2h2(c.x)), c1 = __half22float2(bits2h2(c.y));
    float v0 = (e0.x + a0.x + b0.x + c0.x) * 0.25f;
    float v1 = (e0.y + a0.y + b0.y + c0.y) * 0.25f;
    float v2 = (e1.x + a1.x + b1.x + c1.x) * 0.25f;
    float v3 = (e1.y + a1.y + b1.y + c1.y) * 0.25f;
    u32x2 o;
    o.x = h22bits(__floats2half2_rn(v0, v1));
    o.y = h22bits(__floats2half2_rn(v2, v3));
    *(u32x2*)(ur + (size_t)u * EMBED + q * 4) = o;
}

// ---------- final item rows: 0.25*(emb + r1 + r2 + r3), sliced reads ------
__global__ __launch_bounds__(256) void copy_items(const __half* __restrict__ embS,
                                                  const __half* __restrict__ r1,
                                                  const __half* __restrict__ r2,
                                                  const __half* __restrict__ r3,
                                                  _Float16* __restrict__ ir,
                                                  int ni, int n_nodes) {
    int idx = blockIdx.x * 256 + threadIdx.x;
    int i = idx >> 5;
    int q = idx & 31;
    if (i >= ni) return;
    size_t row = (size_t)(N_USERS_T + i);
    int sl = q >> 2, wq = q & 3;
    size_t p = ((size_t)sl * n_nodes + row) * 4 + wq;
    u32x2 e = ((const u32x2*)embS)[p];
    u32x2 a = ((const u32x2*)r1)[p];
    u32x2 b = ((const u32x2*)r2)[p];
    u32x2 c = ((const u32x2*)r3)[p];
    float2 e0 = __half22float2(bits2h2(e.x)), e1 = __half22float2(bits2h2(e.y));
    float2 a0 = __half22float2(bits2h2(a.x)), a1 = __half22float2(bits2h2(a.y));
    float2 b0 = __half22float2(bits2h2(b.x)), b1 = __half22float2(bits2h2(b.y));
    float2 c0 = __half22float2(bits2h2(c.x)), c1 = __half22float2(bits2h2(c.y));
    float v0 = (e0.x + a0.x + b0.x + c0.x) * 0.25f;
    float v1 = (e0.y + a0.y + b0.y + c0.y) * 0.25f;
    float v2 = (e1.x + a1.x + b1.x + c1.x) * 0.25f;
    float v3 = (e1.y + a1.y + b1.y + c1.y) * 0.25f;
    u32x2 o;
    o.x = h22bits(__floats2half2_rn(v0, v1));
    o.y = h22bits(__floats2half2_rn(v2, v3));
    *(u32x2*)(ir + (size_t)i * EMBED + q * 4) = o;
}

// ---------- MFMA fp16 GEMM: C[nu x nI] = U[nu x 128] * I[nI x 128]^T -------
__global__ __launch_bounds__(256) void gemm_mfma(const _Float16* __restrict__ U,
                                                 const _Float16* __restrict__ I,
                                                 float* __restrict__ C,
                                                 int nu, int nI) {
    int wave = threadIdx.x >> 6;
    int lane = threadIdx.x & 63;
    int i0 = (blockIdx.x * 4 + wave) * 64;
    int u0 = blockIdx.y * 64;
    if (i0 >= nI) return;
    int l16 = lane & 15;
    int kg  = lane >> 4;
    f4 acc[4][4] = {};
    bool inb[4];
    #pragma unroll
    for (int nt = 0; nt < 4; ++nt) inb[nt] = (i0 + nt * 16 + l16) < nI;
    #pragma unroll
    for (int kk = 0; kk < 4; ++kk) {
        const int ko = kk * 32 + kg * 8;
        h8 a[4], b[4];
        #pragma unroll
        for (int mt = 0; mt < 4; ++mt)
            a[mt] = *(const h8*)(U + (size_t)(u0 + mt * 16 + l16) * EMBED + ko);
        #pragma unroll
        for (int nt = 0; nt < 4; ++nt) {
            h8 z = {};
            b[nt] = inb[nt] ? *(const h8*)(I + (size_t)(i0 + nt * 16 + l16) * EMBED + ko) : z;
        }
        #pragma unroll
        for (int mt = 0; mt < 4; ++mt)
            #pragma unroll
            for (int nt = 0; nt < 4; ++nt)
                acc[mt][nt] = __builtin_amdgcn_mfma_f32_16x16x32_f16(a[mt], b[nt], acc[mt][nt], 0, 0, 0);
    }
    #pragma unroll
    for (int mt = 0; mt < 4; ++mt) {
        #pragma unroll
        for (int r = 0; r < 4; ++r) {
            int row = u0 + mt * 16 + kg * 4 + r;
            if (row >= nu) continue;
            float* Cr = C + (size_t)row * nI;
            #pragma unroll
            for (int nt = 0; nt < 4; ++nt) {
                int col = i0 + nt * 16 + l16;
                if (col < nI)
                    __builtin_nontemporal_store(acc[mt][nt][r], Cr + col);
            }
        }
    }
}

extern "C" void kernel_launch(void* const* d_in, const int* in_sizes, int n_in,
                              void* d_out, int out_size, void* d_ws, size_t ws_size,
                              hipStream_t stream) {
    const float* emb   = (const float*)d_in[0];
    const float* ew    = (const float*)d_in[1];
    const int*   esrc  = (const int*)d_in[2];
    const int*   edst  = (const int*)d_in[3];
    const int*   users = (const int*)d_in[4];
    const int n_edges = in_sizes[1];
    const int n_nodes = in_sizes[0] / EMBED;
    const int nu      = in_sizes[4];

    // ---- workspace layout (~27 MB) ----
    char* ws = (char*)d_ws;
    int*      off_end = (int*)ws;                           // 400128 B
    int*      blkhist = (int*)(ws + 400128);                // 400512 B
    int*      cursors = (int*)(ws + 800640);                // 400512 B
    int*      total   = (int*)(ws + 1201152);               // 1664 B
    int*      bbase   = (int*)(ws + 1202816);               // 1664 B
    unsigned* epc     = (unsigned*)(ws + 1204480);          // 12.8 MB
    _Float16* ur      = (_Float16*)(ws + 1204480 + 12800000);           // 256 KB
    _Float16* ir      = (_Float16*)(ws + 1204480 + 12800000 + 262144);  // 12.8 MB

    // ---- d_out doubles as scratch until the final GEMM overwrites it ----
    // All rep buffers use SLICED layout [8][N][16] fp16.
    __half* emb_s   = (__half*)d_out;                       // 25.6 MB
    __half* rep1_s  = emb_s + (size_t)12800000;             // 25.6 MB
    __half* rep2_s  = emb_s + (size_t)2 * 12800000;         // 25.6 MB
    __half* rep3_s  = emb_s + (size_t)3 * 12800000;         // 25.6 MB
    int2*   part_ep = (int2*)(emb_s + (size_t)4 * 12800000);// 25.6 MB
    float*  out     = (float*)d_out;

    const int epb = (n_edges + NBLK - 1) / NBLK;

    // 1) two-level CSR build (compressed edge payload)
    part_hist   <<<NBLK, 256, 0, stream>>>(edst, blkhist, n_edges, epb);
    part_cursors<<<NB,   256, 0, stream>>>(blkhist, cursors, total);
    bucket_base_scan<<<1, 64, 0, stream>>>(total, bbase);
    part_scatter<<<NBLK, 256, 0, stream>>>(esrc, edst, ew, cursors, bbase,
                                           part_ep, n_edges, epb);
    bucket_csr  <<<NB,   512, 0, stream>>>(part_ep, bbase, off_end, epc, n_nodes);

    // 2) fp16 sliced copy of embedding
    dim3 fg((n_nodes * 4 + 255) / 256, 8);
    f2h_slice<<<fg, 256, 0, stream>>>(emb, emb_s, n_nodes);

    // 3) three propagation layers, feature-sharded across XCDs
    const int nbs = (n_nodes + 127) / 128;
    layer_slice<<<nbs * 8, 256, 0, stream>>>(emb_s,  rep1_s, off_end, epc, n_nodes);
    layer_slice<<<nbs * 8, 256, 0, stream>>>(rep1_s, rep2_s, off_end, epc, n_nodes);
    layer_slice<<<nbs * 8, 256, 0, stream>>>(rep2_s, rep3_s, off_end, epc, n_nodes);

    // 4) final rows: 0.25*(emb + r1 + r2 + r3) -> fp16 ur / ir (row-major)
    gather_users<<<(nu * 32 + 255) / 256, 256, 0, stream>>>(users, emb_s, rep1_s, rep2_s, rep3_s, ur, nu, n_nodes);
    copy_items<<<(N_ITEMS * 32 + 255) / 256, 256, 0, stream>>>(emb_s, rep1_s, rep2_s, rep3_s, ir, N_ITEMS, n_nodes);

    // 5) scores = ur @ ir^T via fp16 MFMA (fp32 accumulate)
    dim3 ggrid((N_ITEMS + 255) / 256, (nu + 63) / 64);
    gemm_mfma<<<ggrid, 256, 0, stream>>>(ur, ir, out, nu, N_ITEMS);
}

// Round 14
// 490.203 us; speedup vs baseline: 1.9315x; 1.9315x over previous
//
#include <hip/hip_runtime.h>
#include <hip/hip_bf16.h>
#include <hip/hip_fp16.h>

typedef float f4 __attribute__((ext_vector_type(4)));
typedef unsigned int u32x2 __attribute__((ext_vector_type(2)));
typedef unsigned int u32x4 __attribute__((ext_vector_type(4)));
typedef _Float16 h8 __attribute__((ext_vector_type(8)));

__device__ __forceinline__ __half2 bits2h2(unsigned u) {
    union { unsigned u; __half2 h; } c; c.u = u; return c.h;
}
__device__ __forceinline__ unsigned h22bits(__half2 h) {
    union { unsigned u; __half2 h; } c; c.h = h; return c.u;
}

#define N_NODES   100000
#define EMBED     128
#define N_USERS_T 50000
#define N_ITEMS   50000

#define BSH   8                 // bucket = dst >> 8
#define NB    391               // ceil(100000 / 256)
#define NBLK  256               // partition blocks

// ---------- K1: per-block bucket histogram ----------
__global__ __launch_bounds__(256) void part_hist(const int* __restrict__ dst,
                                                 int* __restrict__ blkhist,
                                                 int n, int epb) {
    __shared__ int h[NB];
    for (int j = threadIdx.x; j < NB; j += 256) h[j] = 0;
    __syncthreads();
    int b = blockIdx.x, s = b * epb, e = min(n, s + epb);
    for (int i = s + (int)threadIdx.x; i < e; i += 256)
        atomicAdd(&h[dst[i] >> BSH], 1);
    __syncthreads();
    for (int j = threadIdx.x; j < NB; j += 256) blkhist[b * NB + j] = h[j];
}

// ---------- K2a: per-bucket exclusive scan across blocks ----------
__global__ __launch_bounds__(256) void part_cursors(const int* __restrict__ blkhist,
                                                    int* __restrict__ cursors,
                                                    int* __restrict__ total) {
    int bu = blockIdx.x, t = threadIdx.x;
    int v = blkhist[t * NB + bu];
    int lane = t & 63, wid = t >> 6;
    int x = v;
    #pragma unroll
    for (int off = 1; off < 64; off <<= 1) {
        int y = __shfl_up(x, off, 64);
        if (lane >= off) x += y;
    }
    __shared__ int ws4[4];
    if (lane == 63) ws4[wid] = x;
    __syncthreads();
    int add = 0;
    for (int j = 0; j < wid; ++j) add += ws4[j];
    cursors[t * NB + bu] = add + x - v;      // exclusive over blocks
    if (t == 255) total[bu] = add + x;       // bucket size
}

// ---------- K2b: bucket base (serial tiny scan) ----------
__global__ void bucket_base_scan(const int* __restrict__ total,
                                 int* __restrict__ base) {
    if (threadIdx.x == 0) {
        int s = 0;
        for (int j = 0; j < NB; ++j) { base[j] = s; s += total[j]; }
        base[NB] = s;
    }
}

// ---------- K3: partition into buckets (block-private slices) ----------
// part entry: .x = src | (dst_low8 << 17), .y = w bits
__global__ __launch_bounds__(256) void part_scatter(const int* __restrict__ src,
                                                    const int* __restrict__ dst,
                                                    const float* __restrict__ w,
                                                    const int* __restrict__ cursors,
                                                    const int* __restrict__ base,
                                                    int2* __restrict__ part,
                                                    int n, int epb) {
    __shared__ int cur[NB];
    int b = blockIdx.x;
    for (int j = threadIdx.x; j < NB; j += 256)
        cur[j] = base[j] + cursors[b * NB + j];
    __syncthreads();
    int s = b * epb, e = min(n, s + epb);
    for (int i = s + (int)threadIdx.x; i < e; i += 256) {
        int d = dst[i];
        int bu = d >> BSH;
        int p = atomicAdd(&cur[bu], 1);
        int2 pe;
        pe.x = src[i] | ((d & 255) << 17);
        pe.y = __float_as_int(w[i]);
        part[p] = pe;
    }
}

// ---------- K4: per-bucket fine CSR; emits compressed edge u32 -------------
// edge u32 = src (17b) | wq (15b fixed-point w*32768)
__global__ __launch_bounds__(512) void bucket_csr(const int2* __restrict__ part,
                                                  const int* __restrict__ base,
                                                  int* __restrict__ off_end,
                                                  unsigned* __restrict__ ep,
                                                  int n_nodes) {
    __shared__ int cnt[256], cur2[256], ws4[4];
    int bu = blockIdx.x, t = threadIdx.x;
    int b0 = base[bu], b1 = base[bu + 1];
    if (t < 256) cnt[t] = 0;
    __syncthreads();
    for (int i = b0 + t; i < b1; i += 512)
        atomicAdd(&cnt[(part[i].x >> 17) & 255], 1);
    __syncthreads();
    int lane = t & 63, wid = t >> 6;
    int v = 0, x = 0;
    if (t < 256) {
        v = cnt[t]; x = v;
        #pragma unroll
        for (int off = 1; off < 64; off <<= 1) {
            int y = __shfl_up(x, off, 64);
            if (lane >= off) x += y;
        }
        if (lane == 63) ws4[wid] = x;
    }
    __syncthreads();
    if (t < 256) {
        int add = 0;
        for (int j = 0; j < wid; ++j) add += ws4[j];
        int incl = add + x;
        int node = (bu << BSH) + t;
        if (node < n_nodes) off_end[node] = b0 + incl;
        cur2[t] = b0 + incl - v;             // exclusive start
    }
    __syncthreads();
    for (int i = b0 + t; i < b1; i += 512) {
        int2 pe = part[i];
        int dloc = (pe.x >> 17) & 255;
        int p = atomicAdd(&cur2[dloc], 1);
        float wf = __int_as_float(pe.y);
        int wq = (int)(wf * 32768.f + 0.5f);
        wq = min(max(wq, 0), 32767);
        ep[p] = (unsigned)(pe.x & 0x1FFFF) | ((unsigned)wq << 17);
    }
}

// ---------- fp32 -> fp16 row conversion ----------
__global__ __launch_bounds__(256) void f2h_kernel(const float* __restrict__ in,
                                                  __half* __restrict__ out, int n4) {
    int i = blockIdx.x * 256 + threadIdx.x;
    if (i < n4) {
        f4 v = ((const f4*)in)[i];
        u32x2 o;
        o.x = h22bits(__floats2half2_rn(v.x, v.y));
        o.y = h22bits(__floats2half2_rn(v.z, v.w));
        ((u32x2*)out)[i] = o;
    }
}

// ---------- propagation layer: fp16 gather -> fp16 rep ----------
// Quarter-wave per edge (16 lanes x 16 B / row), 8 loads in flight, uniform
// trip count (R9 lesson). Plain cached loads/stores (R8: nt-store hurt;
// R12: nt-load hurt). This is the measured optimum configuration (R11).
__global__ __launch_bounds__(256) void layer_kernel(
        const __half* __restrict__ rep_in, __half* __restrict__ rep_out,
        const int* __restrict__ off_end, const unsigned* __restrict__ ep,
        int n_nodes) {
    int node = blockIdx.x * 4 + (threadIdx.x >> 6);
    if (node >= n_nodes) return;
    int lane = threadIdx.x & 63;
    int grp  = lane >> 4;             // 0..3: edge slot within quad
    int l16  = lane & 15;             // 16-B segment of the row
    int beg = (node == 0) ? 0 : off_end[node - 1];
    int end = off_end[node];
    f4 sa = {0.f, 0.f, 0.f, 0.f};     // features l16*8 .. +3
    f4 sb = {0.f, 0.f, 0.f, 0.f};     // features l16*8+4 .. +7
    const u32x4* rp = (const u32x4*)rep_in;   // row = 16 x u32x4

    auto acc1 = [&](unsigned v, u32x4 rv) {
        float wt = (float)(v >> 17) * (1.f / 32768.f);
        float2 f0 = __half22float2(bits2h2(rv.x));
        float2 f1 = __half22float2(bits2h2(rv.y));
        float2 f2 = __half22float2(bits2h2(rv.z));
        float2 f3 = __half22float2(bits2h2(rv.w));
        sa.x = fmaf(wt, f0.x, sa.x);
        sa.y = fmaf(wt, f0.y, sa.y);
        sa.z = fmaf(wt, f1.x, sa.z);
        sa.w = fmaf(wt, f1.y, sa.w);
        sb.x = fmaf(wt, f2.x, sb.x);
        sb.y = fmaf(wt, f2.y, sb.y);
        sb.z = fmaf(wt, f3.x, sb.z);
        sb.w = fmaf(wt, f3.y, sb.w);
    };

    for (int chunk = beg; chunk < end; chunk += 64) {
        int idx = chunk + lane;
        unsigned ev = (idx < end) ? ep[idx] : 0u;
        int m = end - chunk; if (m > 64) m = 64;
        int np = (m + 3) >> 2;            // quad steps: UNIFORM across wave
        int p = 0;
        for (; p + 8 <= np; p += 8) {
            int jb = p * 4 + grp;
            unsigned v0 = __shfl(ev, jb +  0);
            unsigned v1 = __shfl(ev, jb +  4);
            unsigned v2 = __shfl(ev, jb +  8);
            unsigned v3 = __shfl(ev, jb + 12);
            unsigned v4 = __shfl(ev, jb + 16);
            unsigned v5 = __shfl(ev, jb + 20);
            unsigned v6 = __shfl(ev, jb + 24);
            unsigned v7 = __shfl(ev, jb + 28);
            u32x4 r0 = rp[(size_t)(v0 & 0x1FFFF) * 16 + l16];
            u32x4 r1 = rp[(size_t)(v1 & 0x1FFFF) * 16 + l16];
            u32x4 r2 = rp[(size_t)(v2 & 0x1FFFF) * 16 + l16];
            u32x4 r3 = rp[(size_t)(v3 & 0x1FFFF) * 16 + l16];
            u32x4 r4 = rp[(size_t)(v4 & 0x1FFFF) * 16 + l16];
            u32x4 r5 = rp[(size_t)(v5 & 0x1FFFF) * 16 + l16];
            u32x4 r6 = rp[(size_t)(v6 & 0x1FFFF) * 16 + l16];
            u32x4 r7 = rp[(size_t)(v7 & 0x1FFFF) * 16 + l16];
            acc1(v0, r0); acc1(v1, r1); acc1(v2, r2); acc1(v3, r3);
            acc1(v4, r4); acc1(v5, r5); acc1(v6, r6); acc1(v7, r7);
        }
        for (; p < np; ++p) {
            unsigned v = __shfl(ev, p * 4 + grp);
            u32x4 r = rp[(size_t)(v & 0x1FFFF) * 16 + l16];
            acc1(v, r);
        }
    }
    // reduce across the 4 groups (lanes l16, l16+16, l16+32, l16+48)
    sa.x += __shfl_xor(sa.x, 16); sa.y += __shfl_xor(sa.y, 16);
    sa.z += __shfl_xor(sa.z, 16); sa.w += __shfl_xor(sa.w, 16);
    sb.x += __shfl_xor(sb.x, 16); sb.y += __shfl_xor(sb.y, 16);
    sb.z += __shfl_xor(sb.z, 16); sb.w += __shfl_xor(sb.w, 16);
    sa.x += __shfl_xor(sa.x, 32); sa.y += __shfl_xor(sa.y, 32);
    sa.z += __shfl_xor(sa.z, 32); sa.w += __shfl_xor(sa.w, 32);
    sb.x += __shfl_xor(sb.x, 32); sb.y += __shfl_xor(sb.y, 32);
    sb.z += __shfl_xor(sb.z, 32); sb.w += __shfl_xor(sb.w, 32);
    if (grp == 0) {
        u32x4 ov;
        ov.x = h22bits(__floats2half2_rn(sa.x, sa.y));
        ov.y = h22bits(__floats2half2_rn(sa.z, sa.w));
        ov.z = h22bits(__floats2half2_rn(sb.x, sb.y));
        ov.w = h22bits(__floats2half2_rn(sb.z, sb.w));
        ((u32x4*)rep_out)[(size_t)node * 16 + l16] = ov;
    }
}

// ---------- final user rows: 0.25*(emb + r1 + r2 + r3), fp16 out ----------
__global__ __launch_bounds__(256) void gather_users(const int* __restrict__ users,
                                                    const float* __restrict__ emb,
                                                    const __half* __restrict__ r1,
                                                    const __half* __restrict__ r2,
                                                    const __half* __restrict__ r3,
                                                    _Float16* __restrict__ ur, int nu) {
    int idx = blockIdx.x * 256 + threadIdx.x;
    int u = idx >> 5;
    int q = idx & 31;
    if (u >= nu) return;
    size_t row = (size_t)users[u];
    f4 e = *(const f4*)(emb + row * EMBED + q * 4);
    size_t p = row * 32 + q;
    u32x2 a = ((const u32x2*)r1)[p];
    u32x2 b = ((const u32x2*)r2)[p];
    u32x2 c = ((const u32x2*)r3)[p];
    float2 a0 = __half22float2(bits2h2(a.x)), a1 = __half22float2(bits2h2(a.y));
    float2 b0 = __half22float2(bits2h2(b.x)), b1 = __half22float2(bits2h2(b.y));
    float2 c0 = __half22float2(bits2h2(c.x)), c1 = __half22float2(bits2h2(c.y));
    float v0 = (e.x + a0.x + b0.x + c0.x) * 0.25f;
    float v1 = (e.y + a0.y + b0.y + c0.y) * 0.25f;
    float v2 = (e.z + a1.x + b1.x + c1.x) * 0.25f;
    float v3 = (e.w + a1.y + b1.y + c1.y) * 0.25f;
    u32x2 o;
    o.x = h22bits(__floats2half2_rn(v0, v1));
    o.y = h22bits(__floats2half2_rn(v2, v3));
    *(u32x2*)(ur + (size_t)u * EMBED + q * 4) = o;
}

// ---------- final item rows: 0.25*(emb + r1 + r2 + r3), fp16 out ----------
__global__ __launch_bounds__(256) void copy_items(const float* __restrict__ emb,
                                                  const __half* __restrict__ r1,
                                                  const __half* __restrict__ r2,
                                                  const __half* __restrict__ r3,
                                                  _Float16* __restrict__ ir, int ni) {
    int idx = blockIdx.x * 256 + threadIdx.x;
    int i = idx >> 5;
    int q = idx & 31;
    if (i >= ni) return;
    size_t row = (size_t)(N_USERS_T + i);
    f4 e = *(const f4*)(emb + row * EMBED + q * 4);
    size_t p = row * 32 + q;
    u32x2 a = ((const u32x2*)r1)[p];
    u32x2 b = ((const u32x2*)r2)[p];
    u32x2 c = ((const u32x2*)r3)[p];
    float2 a0 = __half22float2(bits2h2(a.x)), a1 = __half22float2(bits2h2(a.y));
    float2 b0 = __half22float2(bits2h2(b.x)), b1 = __half22float2(bits2h2(b.y));
    float2 c0 = __half22float2(bits2h2(c.x)), c1 = __half22float2(bits2h2(c.y));
    float v0 = (e.x + a0.x + b0.x + c0.x) * 0.25f;
    float v1 = (e.y + a0.y + b0.y + c0.y) * 0.25f;
    float v2 = (e.z + a1.x + b1.x + c1.x) * 0.25f;
    float v3 = (e.w + a1.y + b1.y + c1.y) * 0.25f;
    u32x2 o;
    o.x = h22bits(__floats2half2_rn(v0, v1));
    o.y = h22bits(__floats2half2_rn(v2, v3));
    *(u32x2*)(ir + (size_t)i * EMBED + q * 4) = o;
}

// ---------- MFMA fp16 GEMM: C[nu x nI] = U[nu x 128] * I[nI x 128]^T -------
__global__ __launch_bounds__(256) void gemm_mfma(const _Float16* __restrict__ U,
                                                 const _Float16* __restrict__ I,
                                                 float* __restrict__ C,
                                                 int nu, int nI) {
    int wave = threadIdx.x >> 6;
    int lane = threadIdx.x & 63;
    int i0 = (blockIdx.x * 4 + wave) * 64;
    int u0 = blockIdx.y * 64;
    if (i0 >= nI) return;
    int l16 = lane & 15;
    int kg  = lane >> 4;
    f4 acc[4][4] = {};
    bool inb[4];
    #pragma unroll
    for (int nt = 0; nt < 4; ++nt) inb[nt] = (i0 + nt * 16 + l16) < nI;
    #pragma unroll
    for (int kk = 0; kk < 4; ++kk) {
        const int ko = kk * 32 + kg * 8;
        h8 a[4], b[4];
        #pragma unroll
        for (int mt = 0; mt < 4; ++mt)
            a[mt] = *(const h8*)(U + (size_t)(u0 + mt * 16 + l16) * EMBED + ko);
        #pragma unroll
        for (int nt = 0; nt < 4; ++nt) {
            h8 z = {};
            b[nt] = inb[nt] ? *(const h8*)(I + (size_t)(i0 + nt * 16 + l16) * EMBED + ko) : z;
        }
        #pragma unroll
        for (int mt = 0; mt < 4; ++mt)
            #pragma unroll
            for (int nt = 0; nt < 4; ++nt)
                acc[mt][nt] = __builtin_amdgcn_mfma_f32_16x16x32_f16(a[mt], b[nt], acc[mt][nt], 0, 0, 0);
    }
    #pragma unroll
    for (int mt = 0; mt < 4; ++mt) {
        #pragma unroll
        for (int r = 0; r < 4; ++r) {
            int row = u0 + mt * 16 + kg * 4 + r;
            if (row >= nu) continue;
            float* Cr = C + (size_t)row * nI;
            #pragma unroll
            for (int nt = 0; nt < 4; ++nt) {
                int col = i0 + nt * 16 + l16;
                if (col < nI)
                    __builtin_nontemporal_store(acc[mt][nt][r], Cr + col);
            }
        }
    }
}

extern "C" void kernel_launch(void* const* d_in, const int* in_sizes, int n_in,
                              void* d_out, int out_size, void* d_ws, size_t ws_size,
                              hipStream_t stream) {
    const float* emb   = (const float*)d_in[0];
    const float* ew    = (const float*)d_in[1];
    const int*   esrc  = (const int*)d_in[2];
    const int*   edst  = (const int*)d_in[3];
    const int*   users = (const int*)d_in[4];
    const int n_edges = in_sizes[1];
    const int n_nodes = in_sizes[0] / EMBED;
    const int nu      = in_sizes[4];

    // ---- workspace layout (~27 MB) ----
    char* ws = (char*)d_ws;
    int*      off_end = (int*)ws;                           // 400128 B
    int*      blkhist = (int*)(ws + 400128);                // 400512 B
    int*      cursors = (int*)(ws + 800640);                // 400512 B
    int*      total   = (int*)(ws + 1201152);               // 1664 B
    int*      bbase   = (int*)(ws + 1202816);               // 1664 B
    unsigned* epc     = (unsigned*)(ws + 1204480);          // 12.8 MB
    _Float16* ur      = (_Float16*)(ws + 1204480 + 12800000);           // 256 KB
    _Float16* ir      = (_Float16*)(ws + 1204480 + 12800000 + 262144);  // 12.8 MB

    // ---- d_out doubles as scratch until the final GEMM overwrites it ----
    __half* emb_h   = (__half*)d_out;                       // 25.6 MB
    __half* rep1_h  = emb_h + (size_t)12800000;             // 25.6 MB
    __half* rep2_h  = emb_h + (size_t)2 * 12800000;         // 25.6 MB
    __half* rep3_h  = emb_h + (size_t)3 * 12800000;         // 25.6 MB
    int2*   part_ep = (int2*)(emb_h + (size_t)4 * 12800000);// 25.6 MB
    float*  out     = (float*)d_out;

    const int epb = (n_edges + NBLK - 1) / NBLK;

    // 1) two-level CSR build (compressed edge payload)
    part_hist   <<<NBLK, 256, 0, stream>>>(edst, blkhist, n_edges, epb);
    part_cursors<<<NB,   256, 0, stream>>>(blkhist, cursors, total);
    bucket_base_scan<<<1, 64, 0, stream>>>(total, bbase);
    part_scatter<<<NBLK, 256, 0, stream>>>(esrc, edst, ew, cursors, bbase,
                                           part_ep, n_edges, epb);
    bucket_csr  <<<NB,   512, 0, stream>>>(part_ep, bbase, off_end, epc, n_nodes);

    // 2) fp16 copy of embedding for layer-1 gathers
    int n4 = n_nodes * EMBED / 4;
    f2h_kernel<<<(n4 + 255) / 256, 256, 0, stream>>>(emb, emb_h, n4);

    // 3) three propagation layers (fp16 gather, fp32 math, fp16 rep out)
    const int lgrid = (n_nodes + 3) / 4;
    layer_kernel<<<lgrid, 256, 0, stream>>>(emb_h,  rep1_h, off_end, epc, n_nodes);
    layer_kernel<<<lgrid, 256, 0, stream>>>(rep1_h, rep2_h, off_end, epc, n_nodes);
    layer_kernel<<<lgrid, 256, 0, stream>>>(rep2_h, rep3_h, off_end, epc, n_nodes);

    // 4) final rows: 0.25*(emb + r1 + r2 + r3) -> fp16 ur / ir
    gather_users<<<(nu * 32 + 255) / 256, 256, 0, stream>>>(users, emb, rep1_h, rep2_h, rep3_h, ur, nu);
    copy_items<<<(N_ITEMS * 32 + 255) / 256, 256, 0, stream>>>(emb, rep1_h, rep2_h, rep3_h, ir, N_ITEMS);

    // 5) scores = ur @ ir^T via fp16 MFMA (fp32 accumulate)
    dim3 ggrid((N_ITEMS + 255) / 256, (nu + 63) / 64);
    gemm_mfma<<<ggrid, 256, 0, stream>>>(ur, ir, out, nu, N_ITEMS);
}